// Round 2
// baseline (355.122 us; speedup 1.0000x reference)
//
#include <hip/hip_runtime.h>

#define NS 8
#define NC 21
#define HW (512*512)
#define OLD 16
#define IGNORE_IDX 255
#define HBLK 64                       // hist blocks per sample
#define LGRID (NS * (HW/4) / 256)     // 2048 loss blocks

// ws layout (bytes) — nothing requires pre-zeroed memory
#define HPART_OFF  0                  // int [NS*HBLK][8]  = 16384 B (6 used, pad 8)
#define WGT_OFF    16384              // float[NS*NC]      = 672 B (pad to 1024)
#define PSUM_OFF   17408              // float[LGRID]      = 8192 B
#define PCNT_OFF   25600              // int  [LGRID]      = 8192 B
#define TICKET_OFF 33792              // unsigned int

__device__ __forceinline__ float get4(const float4& v, int j) {
    switch (j) { case 0: return v.x; case 1: return v.y; case 2: return v.z; default: return v.w; }
}

// ---------------- hist: per-block partial counters, no atomics, no init ----------------
__global__ void __launch_bounds__(256) hist_kernel(const int* __restrict__ tgt,
                                                   int* __restrict__ hpart) {
    int n   = blockIdx.x >> 6;
    int blk = blockIdx.x & 63;
    const int4* t4 = reinterpret_cast<const int4*>(tgt + (size_t)n * HW);
    int c[6] = {0, 0, 0, 0, 0, 0};
#pragma unroll
    for (int it = 0; it < 4; ++it) {
        int idx = blk * 1024 + it * 256 + threadIdx.x;   // HW/4 = 65536 = 64*1024
        int4 t = t4[idx];
#define COUNT_LAB(T) { int lab = (T) < OLD ? 0 : (T);                       \
        c[0] += (lab == 0);  c[1] += (lab == 16); c[2] += (lab == 17);      \
        c[3] += (lab == 18); c[4] += (lab == 19); c[5] += (lab == 20); }
        COUNT_LAB(t.x) COUNT_LAB(t.y) COUNT_LAB(t.z) COUNT_LAB(t.w)
#undef COUNT_LAB
    }
#pragma unroll
    for (int off = 32; off > 0; off >>= 1)
#pragma unroll
        for (int k = 0; k < 6; ++k) c[k] += __shfl_down(c[k], off, 64);

    __shared__ int sh[4][6];
    int wave = threadIdx.x >> 6;
    if ((threadIdx.x & 63) == 0)
#pragma unroll
        for (int k = 0; k < 6; ++k) sh[wave][k] = c[k];
    __syncthreads();
    if (threadIdx.x == 0) {
        int* out = hpart + blockIdx.x * 8;
#pragma unroll
        for (int k = 0; k < 6; ++k)
            out[k] = sh[0][k] + sh[1][k] + sh[2][k] + sh[3][k];
    }
}

// ---------------- weight: reduce partials + reference hist logic + init ticket ----------------
__global__ void weight_kernel(const int* __restrict__ hpart,
                              float* __restrict__ wgt,
                              unsigned int* __restrict__ ticket) {
    __shared__ int shist[NS][6];
    int t = threadIdx.x;
    if (t < NS * 6) {
        int n = t / 6, k = t % 6;
        int s = 0;
        for (int b = 0; b < HBLK; ++b) s += hpart[(n * HBLK + b) * 8 + k];
        shist[n][k] = s;
    }
    if (t == 0) *ticket = 0;
    __syncthreads();
    if (t < NS * NC) {
        int n = t / NC, c = t % NC;
        // adjusted hist per reference: h[0]=cnt0 (collapse==raw since 1..15 empty),
        // 1..15 -> 0, 16..20 -> raw; empty non-old classes -> 1
        float h[6];
        float total = 0.0f;
#pragma unroll
        for (int k = 0; k < 6; ++k) {
            int raw = shist[n][k];
            h[k] = (raw == 0) ? 1.0f : (float)raw;
            total += h[k];
        }
        float w;
        if (c >= 1 && c < OLD)      w = 0.0f;
        else if (c == 0)            w = total / h[0];
        else                        w = total / h[c - OLD + 1];   // c in 16..20 -> k 1..5
        wgt[t] = w;
    }
}

// ---------------- loss: float4 channel loads + last-block-done finalize ----------------
__global__ void __launch_bounds__(256) loss_kernel(const float* __restrict__ in,
                                                   const int* __restrict__ tgt,
                                                   const float* __restrict__ wgt,
                                                   float* __restrict__ psum,
                                                   int* __restrict__ pcnt,
                                                   unsigned int* __restrict__ ticket,
                                                   float* __restrict__ out) {
    const int perN = HW / 4;                              // 65536 groups per sample
    int gid = blockIdx.x * 256 + threadIdx.x;
    int n   = gid / perN;
    int p   = (gid - n * perN) * 4;

    __shared__ float sw[NC];
    if (threadIdx.x < NC) sw[threadIdx.x] = wgt[n * NC + threadIdx.x];
    __syncthreads();

    const float* base = in + (size_t)n * (NC * HW) + p;
    int4 t = *reinterpret_cast<const int4*>(tgt + (size_t)n * HW + p);

    float4 v[NC];
#pragma unroll
    for (int c = 0; c < NC; ++c)
        v[c] = *reinterpret_cast<const float4*>(base + (size_t)c * HW);

    int labs[4] = {t.x, t.y, t.z, t.w};
    float partial = 0.0f;
    int cnt = 0;
#pragma unroll
    for (int j = 0; j < 4; ++j) {
        int lab = labs[j];
        lab = lab < OLD ? 0 : lab;
        float m16 = -3.4e38f;
#pragma unroll
        for (int c = 0; c < OLD; ++c) m16 = fmaxf(m16, get4(v[c], j));
        float s16 = 0.0f;
#pragma unroll
        for (int c = 0; c < OLD; ++c) s16 += __expf(get4(v[c], j) - m16);
        float m = m16;
#pragma unroll
        for (int c = OLD; c < NC; ++c) m = fmaxf(m, get4(v[c], j));
        float s  = s16 * __expf(m16 - m);
        float xl = 0.0f;
#pragma unroll
        for (int c = OLD; c < NC; ++c) {
            float x = get4(v[c], j);
            s += __expf(x - m);
            xl = (lab == c) ? x : xl;
        }
        float den   = m + __logf(s);
        float lse16 = m16 + __logf(s16);
        float val   = (lab == 0 ? lse16 : xl) - den;
        int  widx   = (lab < NC) ? lab : 0;
        bool valid  = (lab != IGNORE_IDX);
        if (valid) { partial += sw[widx] * val; cnt++; }
    }

#pragma unroll
    for (int off = 32; off > 0; off >>= 1) {
        partial += __shfl_down(partial, off, 64);
        cnt     += __shfl_down(cnt, off, 64);
    }
    __shared__ float sp[4];
    __shared__ int   sc[4];
    __shared__ bool  amLast;
    int wave = threadIdx.x >> 6;
    if ((threadIdx.x & 63) == 0) { sp[wave] = partial; sc[wave] = cnt; }
    __syncthreads();
    if (threadIdx.x == 0) {
        psum[blockIdx.x] = sp[0] + sp[1] + sp[2] + sp[3];
        pcnt[blockIdx.x] = sc[0] + sc[1] + sc[2] + sc[3];
        __threadfence();                                   // release partials
        unsigned int tk = atomicAdd(ticket, 1u);
        amLast = (tk == (unsigned int)(LGRID - 1));
    }
    __syncthreads();

    if (amLast) {
        __threadfence();                                   // acquire partials
        const volatile float* vs = (const volatile float*)psum;
        const volatile int*   vc = (const volatile int*)pcnt;
        double dsum = 0.0;
        long long dcnt = 0;
        for (int i = threadIdx.x; i < LGRID; i += 256) {
            dsum += (double)vs[i];
            dcnt += vc[i];
        }
#pragma unroll
        for (int off = 32; off > 0; off >>= 1) {
            dsum += __shfl_down(dsum, off, 64);
            dcnt += __shfl_down(dcnt, off, 64);
        }
        __shared__ double fs[4];
        __shared__ long long fc[4];
        if ((threadIdx.x & 63) == 0) { fs[wave] = dsum; fc[wave] = dcnt; }
        __syncthreads();
        if (threadIdx.x == 0) {
            double S = fs[0] + fs[1] + fs[2] + fs[3];
            long long Cn = fc[0] + fc[1] + fc[2] + fc[3];
            out[0] = (Cn > 0) ? (float)(-S / (double)Cn) : 0.0f;
        }
    }
}

extern "C" void kernel_launch(void* const* d_in, const int* in_sizes, int n_in,
                              void* d_out, int out_size, void* d_ws, size_t ws_size,
                              hipStream_t stream) {
    const float* inputs  = (const float*)d_in[0];
    const int*   targets = (const int*)d_in[1];
    float*       out     = (float*)d_out;

    char* ws = (char*)d_ws;
    int*          hpart  = (int*)(ws + HPART_OFF);
    float*        wgt    = (float*)(ws + WGT_OFF);
    float*        psum   = (float*)(ws + PSUM_OFF);
    int*          pcnt   = (int*)(ws + PCNT_OFF);
    unsigned int* ticket = (unsigned int*)(ws + TICKET_OFF);

    hist_kernel<<<NS * HBLK, 256, 0, stream>>>(targets, hpart);
    weight_kernel<<<1, 256, 0, stream>>>(hpart, wgt, ticket);
    loss_kernel<<<LGRID, 256, 0, stream>>>(inputs, targets, wgt, psum, pcnt, ticket, out);
}

// Round 3
// 256.427 us; speedup vs baseline: 1.3849x; 1.3849x over previous
//
#include <hip/hip_runtime.h>

#define NS 8
#define NC 21
#define HW (512*512)
#define OLD 16
#define IGNORE_IDX 255
#define HBLK 64                       // hist blocks per sample
#define LBLK 64                       // loss blocks per sample
#define LITER 4                       // groups (of 4 px) per thread

// ws layout (bytes) — nothing requires pre-zeroed memory
#define HPART_OFF 0                   // int [NS*HBLK][8] = 16384 B
#define WGT_OFF   16384               // float[NS*NC]
#define SUM_OFF   17408               // double (zeroed by weight_kernel)
#define CNT_OFF   17416               // int    (zeroed by weight_kernel)

__device__ __forceinline__ float get4(const float4& v, int j) {
    switch (j) { case 0: return v.x; case 1: return v.y; case 2: return v.z; default: return v.w; }
}

// ---------------- hist: per-block partial counters, no atomics, no init ----------------
__global__ void __launch_bounds__(256) hist_kernel(const int* __restrict__ tgt,
                                                   int* __restrict__ hpart) {
    int n   = blockIdx.x >> 6;
    int blk = blockIdx.x & 63;
    const int4* t4 = reinterpret_cast<const int4*>(tgt + (size_t)n * HW);
    int c[6] = {0, 0, 0, 0, 0, 0};
#pragma unroll
    for (int it = 0; it < 4; ++it) {
        int idx = blk * 1024 + it * 256 + threadIdx.x;   // HW/4 = 65536 = 64*1024
        int4 t = t4[idx];
#define COUNT_LAB(T) { int lab = (T) < OLD ? 0 : (T);                       \
        c[0] += (lab == 0);  c[1] += (lab == 16); c[2] += (lab == 17);      \
        c[3] += (lab == 18); c[4] += (lab == 19); c[5] += (lab == 20); }
        COUNT_LAB(t.x) COUNT_LAB(t.y) COUNT_LAB(t.z) COUNT_LAB(t.w)
#undef COUNT_LAB
    }
#pragma unroll
    for (int off = 32; off > 0; off >>= 1)
#pragma unroll
        for (int k = 0; k < 6; ++k) c[k] += __shfl_down(c[k], off, 64);

    __shared__ int sh[4][6];
    int wave = threadIdx.x >> 6;
    if ((threadIdx.x & 63) == 0)
#pragma unroll
        for (int k = 0; k < 6; ++k) sh[wave][k] = c[k];
    __syncthreads();
    if (threadIdx.x == 0) {
        int* o = hpart + blockIdx.x * 8;
#pragma unroll
        for (int k = 0; k < 6; ++k)
            o[k] = sh[0][k] + sh[1][k] + sh[2][k] + sh[3][k];
    }
}

// ---------------- weight: reduce partials + reference hist logic + zero accumulators ----------------
__global__ void weight_kernel(const int* __restrict__ hpart,
                              float* __restrict__ wgt,
                              double* __restrict__ sum_acc,
                              int* __restrict__ cnt_acc) {
    __shared__ int shist[NS][6];
    int t = threadIdx.x;
    if (t < NS * 6) {
        int n = t / 6, k = t % 6;
        int s = 0;
        for (int b = 0; b < HBLK; ++b) s += hpart[(n * HBLK + b) * 8 + k];
        shist[n][k] = s;
    }
    if (t == 0) { *sum_acc = 0.0; *cnt_acc = 0; }
    __syncthreads();
    if (t < NS * NC) {
        int n = t / NC, c = t % NC;
        // adjusted hist per reference: 1..15 -> 0 (old classes), 16..20 raw,
        // class 0 = collapse of 0..15 (== raw cnt0 since 1..15 are empty by
        // construction), empty non-old classes -> 1. RATIO == 1.0.
        float h[6];
        float total = 0.0f;
#pragma unroll
        for (int k = 0; k < 6; ++k) {
            int raw = shist[n][k];
            h[k] = (raw == 0) ? 1.0f : (float)raw;
            total += h[k];
        }
        float w;
        if (c >= 1 && c < OLD)      w = 0.0f;
        else if (c == 0)            w = total / h[0];
        else                        w = total / h[c - OLD + 1];   // c in 16..20 -> k 1..5
        wgt[t] = w;
    }
}

// ---------------- loss: LITER groups/thread, fence-free atomic epilogue ----------------
__global__ void __launch_bounds__(256) loss_kernel(const float* __restrict__ in,
                                                   const int* __restrict__ tgt,
                                                   const float* __restrict__ wgt,
                                                   double* __restrict__ sum_acc,
                                                   int* __restrict__ cnt_acc) {
    int n   = blockIdx.x / LBLK;
    int blk = blockIdx.x % LBLK;

    __shared__ float sw[NC];
    if (threadIdx.x < NC) sw[threadIdx.x] = wgt[n * NC + threadIdx.x];
    __syncthreads();

    const float* inN = in + (size_t)n * (NC * HW);
    const int4*  t4  = reinterpret_cast<const int4*>(tgt + (size_t)n * HW);

    float partial = 0.0f;
    int cnt = 0;

#pragma unroll 1
    for (int it = 0; it < LITER; ++it) {
        int g = (blk * LITER + it) * 256 + threadIdx.x;   // group idx within sample
        int p = g * 4;
        int4 t = t4[g];

        float4 v[NC];
#pragma unroll
        for (int c = 0; c < NC; ++c)
            v[c] = *reinterpret_cast<const float4*>(inN + (size_t)c * HW + p);

        int labs[4] = {t.x, t.y, t.z, t.w};
#pragma unroll
        for (int j = 0; j < 4; ++j) {
            int lab = labs[j];
            lab = lab < OLD ? 0 : lab;
            float m16 = -3.4e38f;
#pragma unroll
            for (int c = 0; c < OLD; ++c) m16 = fmaxf(m16, get4(v[c], j));
            float s16 = 0.0f;
#pragma unroll
            for (int c = 0; c < OLD; ++c) s16 += __expf(get4(v[c], j) - m16);
            float m = m16;
#pragma unroll
            for (int c = OLD; c < NC; ++c) m = fmaxf(m, get4(v[c], j));
            float s  = s16 * __expf(m16 - m);
            float xl = 0.0f;
#pragma unroll
            for (int c = OLD; c < NC; ++c) {
                float x = get4(v[c], j);
                s += __expf(x - m);
                xl = (lab == c) ? x : xl;
            }
            float den   = m + __logf(s);
            float lse16 = m16 + __logf(s16);
            float val   = (lab == 0 ? lse16 : xl) - den;
            int  widx   = (lab < NC) ? lab : 0;
            bool valid  = (lab != IGNORE_IDX);
            if (valid) { partial += sw[widx] * val; cnt++; }
        }
    }

#pragma unroll
    for (int off = 32; off > 0; off >>= 1) {
        partial += __shfl_down(partial, off, 64);
        cnt     += __shfl_down(cnt, off, 64);
    }
    __shared__ float sp[4];
    __shared__ int   sc[4];
    int wave = threadIdx.x >> 6;
    if ((threadIdx.x & 63) == 0) { sp[wave] = partial; sc[wave] = cnt; }
    __syncthreads();
    if (threadIdx.x == 0) {
        atomicAdd(sum_acc, (double)(sp[0] + sp[1] + sp[2] + sp[3]));
        atomicAdd(cnt_acc, sc[0] + sc[1] + sc[2] + sc[3]);
    }
}

__global__ void finalize_kernel(const double* __restrict__ sum_acc,
                                const int* __restrict__ cnt_acc,
                                float* __restrict__ out) {
    if (threadIdx.x == 0) {
        int c = *cnt_acc;
        out[0] = (c > 0) ? (float)(-(*sum_acc) / (double)c) : 0.0f;
    }
}

extern "C" void kernel_launch(void* const* d_in, const int* in_sizes, int n_in,
                              void* d_out, int out_size, void* d_ws, size_t ws_size,
                              hipStream_t stream) {
    const float* inputs  = (const float*)d_in[0];
    const int*   targets = (const int*)d_in[1];
    float*       out     = (float*)d_out;

    char* ws = (char*)d_ws;
    int*    hpart   = (int*)(ws + HPART_OFF);
    float*  wgt     = (float*)(ws + WGT_OFF);
    double* sum_acc = (double*)(ws + SUM_OFF);
    int*    cnt_acc = (int*)(ws + CNT_OFF);

    hist_kernel<<<NS * HBLK, 256, 0, stream>>>(targets, hpart);
    weight_kernel<<<1, 256, 0, stream>>>(hpart, wgt, sum_acc, cnt_acc);
    loss_kernel<<<NS * LBLK, 256, 0, stream>>>(inputs, targets, wgt, sum_acc, cnt_acc);
    finalize_kernel<<<1, 64, 0, stream>>>(sum_acc, cnt_acc, out);
}